// Round 1
// baseline (2138.307 us; speedup 1.0000x reference)
//
#include <hip/hip_runtime.h>

// Problem constants (fixed by setup_inputs; attn_num=5, d_delay=10 are python ints)
#define B_    1024
#define L_    512
#define H_    128
#define TH_   384   // 3*H
#define NIN_  2
#define ATTN_ 5
#define DLY_  10

typedef __bf16 bf16x8 __attribute__((ext_vector_type(8)));
typedef unsigned short ushort8 __attribute__((ext_vector_type(8)));
typedef float floatx4 __attribute__((ext_vector_type(4)));

__device__ __forceinline__ unsigned short f2bf(float f) {
  unsigned int x = __builtin_bit_cast(unsigned int, f);
  x += 0x7fffu + ((x >> 16) & 1u);          // RNE
  return (unsigned short)(x >> 16);
}
__device__ __forceinline__ float bf2f(unsigned short u) {
  unsigned int x = ((unsigned int)u) << 16;
  return __builtin_bit_cast(float, x);
}
__device__ __forceinline__ float sigm(float x) { return 1.0f / (1.0f + __expf(-x)); }
__device__ __forceinline__ float tanh_(float x) {
  x = fminf(15.0f, fmaxf(-15.0f, x));
  float e = __expf(-2.0f * x);
  return (1.0f - e) / (1.0f + e);
}
__device__ __forceinline__ floatx4 mfma16(bf16x8 a, bf16x8 b, floatx4 c) {
  return __builtin_amdgcn_mfma_f32_16x16x32_bf16(a, b, c, 0, 0, 0);
}

// ---------------------------------------------------------------------------
// Fused 2-layer GRU, persistent over all 512 steps. One block = 16 batch rows
// of one stack. 512 threads = 8 waves; wave w owns gate N-tiles {w, 8+w, 16+w}
// (one r, one z, one n tile, all for gate dims [16w,16w+16)).
// All weight B-fragments live in registers (3 matrices * 12 frags = 144 VGPR).
// MFMA layouts (per guide, HW-verified): A[m=lane&15][k=(lane>>4)*8+j],
// B[k=(lane>>4)*8+j][n=lane&15], D[row=(lane>>4)*4+reg][col=lane&15].
// ---------------------------------------------------------------------------
__global__ __launch_bounds__(512, 2)
void gru_stack_kernel(
    const float* __restrict__ recv,
    const float* __restrict__ wih0_1, const float* __restrict__ whh0_1,
    const float* __restrict__ bih0_1, const float* __restrict__ bhh0_1,
    const float* __restrict__ wih1_1, const float* __restrict__ whh1_1,
    const float* __restrict__ bih1_1, const float* __restrict__ bhh1_1,
    const float* __restrict__ wih0_2, const float* __restrict__ whh0_2,
    const float* __restrict__ bih0_2, const float* __restrict__ bhh0_2,
    const float* __restrict__ wih1_2, const float* __restrict__ whh1_2,
    const float* __restrict__ bih1_2, const float* __restrict__ bhh1_2,
    unsigned short* __restrict__ r1, unsigned short* __restrict__ r2)
{
  const int bid  = blockIdx.x;        // 0..127
  const int stk  = bid >> 6;          // 0: stack1, 1: stack2
  const int b0   = (bid & 63) * 16;
  const int tid  = threadIdx.x;
  const int wave = tid >> 6;
  const int lane = tid & 63;
  const int lcol = lane & 15;
  const int lquad = lane >> 4;

  const float* wih0 = stk ? wih0_2 : wih0_1;
  const float* whh0 = stk ? whh0_2 : whh0_1;
  const float* bih0 = stk ? bih0_2 : bih0_1;
  const float* bhh0 = stk ? bhh0_2 : bhh0_1;
  const float* wih1 = stk ? wih1_2 : wih1_1;
  const float* whh1 = stk ? whh1_2 : whh1_1;
  const float* bih1 = stk ? bih1_2 : bih1_1;
  const float* bhh1 = stk ? bhh1_2 : bhh1_1;
  unsigned short* rout = stk ? r2 : r1;

  // G cols: [0..255] r,z (ih+hh combined); [256..383] gi_n; [384..511] gh_n
  __shared__ float G[16][516];                       // 33024 B (pad: write groups land 2-way)
  __shared__ float h0f[16][H_];                      // fp32 master h, layer0
  __shared__ float h1f[16][H_];
  __shared__ __attribute__((aligned(16))) unsigned short h0b[16][H_ + 8];  // bf16 copy for MFMA A
  __shared__ __attribute__((aligned(16))) unsigned short h1b[16][H_ + 8];
  __shared__ float wih0s[TH_][2];                    // layer0 input weights (NIN=2)
  __shared__ float biasC0[256], biasC1[256];         // b_ih+b_hh for r,z gates
  __shared__ float bihn0[128], bhhn0[128], bihn1[128], bhhn1[128];
  // total ~65280 B

  // --- load loop-invariant weight fragments into registers (once) ---
  bf16x8 Whh0[3][4], Wih1[3][4], Whh1[3][4];
  {
    const int gb[3] = {16 * wave, 128 + 16 * wave, 256 + 16 * wave};
#pragma unroll
    for (int ti = 0; ti < 3; ++ti) {
      const int g = gb[ti] + lcol;
#pragma unroll
      for (int ks = 0; ks < 4; ++ks) {
        const float* s0 = whh0 + g * H_ + ks * 32 + lquad * 8;
        const float* s1 = wih1 + g * H_ + ks * 32 + lquad * 8;
        const float* s2 = whh1 + g * H_ + ks * 32 + lquad * 8;
        ushort8 u0, u1, u2;
#pragma unroll
        for (int j = 0; j < 8; ++j) { u0[j] = f2bf(s0[j]); u1[j] = f2bf(s1[j]); u2[j] = f2bf(s2[j]); }
        Whh0[ti][ks] = __builtin_bit_cast(bf16x8, u0);
        Wih1[ti][ks] = __builtin_bit_cast(bf16x8, u1);
        Whh1[ti][ks] = __builtin_bit_cast(bf16x8, u2);
      }
    }
  }
  for (int i = tid; i < TH_ * 2; i += 512) wih0s[i >> 1][i & 1] = wih0[i];
  for (int i = tid; i < 256; i += 512) { biasC0[i] = bih0[i] + bhh0[i]; biasC1[i] = bih1[i] + bhh1[i]; }
  for (int i = tid; i < 128; i += 512) {
    bihn0[i] = bih0[256 + i]; bhhn0[i] = bhh0[256 + i];
    bihn1[i] = bih1[256 + i]; bhhn1[i] = bhh1[256 + i];
  }
  for (int i = tid; i < 16 * H_; i += 512) { h0f[i >> 7][i & 127] = 0.f; h1f[i >> 7][i & 127] = 0.f; }
  for (int i = tid; i < 16 * (H_ + 8); i += 512) {
    h0b[i / (H_ + 8)][i % (H_ + 8)] = 0; h1b[i / (H_ + 8)][i % (H_ + 8)] = 0;
  }
  __syncthreads();

  const int rowg = tid >> 7;    // update-phase: row group 0..3
  const int dcol = tid & 127;   // update-phase: hidden dim

  for (int t = 0; t < L_; ++t) {
    // ---- phase 1: gh0 = h0 @ w_hh0^T (MFMA) ----
    {
      floatx4 aR = {0.f,0.f,0.f,0.f}, aZ = {0.f,0.f,0.f,0.f}, aN = {0.f,0.f,0.f,0.f};
#pragma unroll
      for (int ks = 0; ks < 4; ++ks) {
        bf16x8 af = *(const bf16x8*)&h0b[lcol][ks * 32 + lquad * 8];
        aR = mfma16(af, Whh0[0][ks], aR);
        aZ = mfma16(af, Whh0[1][ks], aZ);
        aN = mfma16(af, Whh0[2][ks], aN);
      }
      const int colR = 16 * wave + lcol, rb = lquad * 4;
#pragma unroll
      for (int r = 0; r < 4; ++r) {
        G[rb + r][colR]       = aR[r];
        G[rb + r][128 + colR] = aZ[r];
        G[rb + r][384 + colR] = aN[r];
      }
    }
    __syncthreads();
    // ---- layer0 elementwise update (gi from NIN=2 input computed inline, fp32) ----
#pragma unroll
    for (int i = 0; i < 4; ++i) {
      const int row = rowg * 4 + i;
      const float x0 = recv[(b0 + row) * (L_ * NIN_) + t * NIN_ + 0];
      const float x1 = recv[(b0 + row) * (L_ * NIN_) + t * NIN_ + 1];
      const float gr = G[row][dcol]       + x0 * wih0s[dcol][0]       + x1 * wih0s[dcol][1]       + biasC0[dcol];
      const float gz = G[row][128 + dcol] + x0 * wih0s[128 + dcol][0] + x1 * wih0s[128 + dcol][1] + biasC0[128 + dcol];
      const float gni = x0 * wih0s[256 + dcol][0] + x1 * wih0s[256 + dcol][1] + bihn0[dcol];
      const float gnh = G[row][384 + dcol] + bhhn0[dcol];
      const float rG = sigm(gr), zG = sigm(gz);
      const float nG = tanh_(gni + rG * gnh);
      const float hn = (1.f - zG) * nG + zG * h0f[row][dcol];
      h0f[row][dcol] = hn;
      h0b[row][dcol] = f2bf(hn);
    }
    __syncthreads();
    // ---- phase 2: gi1 = h0_new @ w_ih1^T ; gh1 = h1 @ w_hh1^T (r,z share acc) ----
    {
      floatx4 bR = {0.f,0.f,0.f,0.f}, bZ = {0.f,0.f,0.f,0.f};
      floatx4 bGi = {0.f,0.f,0.f,0.f}, bGh = {0.f,0.f,0.f,0.f};
#pragma unroll
      for (int ks = 0; ks < 4; ++ks) {
        bf16x8 a0 = *(const bf16x8*)&h0b[lcol][ks * 32 + lquad * 8];
        bf16x8 a1 = *(const bf16x8*)&h1b[lcol][ks * 32 + lquad * 8];
        bR = mfma16(a0, Wih1[0][ks], bR); bR = mfma16(a1, Whh1[0][ks], bR);
        bZ = mfma16(a0, Wih1[1][ks], bZ); bZ = mfma16(a1, Whh1[1][ks], bZ);
        bGi = mfma16(a0, Wih1[2][ks], bGi);   // gi_n (kept separate: r scales hh-part only)
        bGh = mfma16(a1, Whh1[2][ks], bGh);   // gh_n
      }
      const int colR = 16 * wave + lcol, rb = lquad * 4;
#pragma unroll
      for (int r = 0; r < 4; ++r) {
        G[rb + r][colR]       = bR[r];
        G[rb + r][128 + colR] = bZ[r];
        G[rb + r][256 + colR] = bGi[r];
        G[rb + r][384 + colR] = bGh[r];
      }
    }
    __syncthreads();
    // ---- layer1 elementwise update + store r ----
#pragma unroll
    for (int i = 0; i < 4; ++i) {
      const int row = rowg * 4 + i;
      const float gr = G[row][dcol]       + biasC1[dcol];
      const float gz = G[row][128 + dcol] + biasC1[128 + dcol];
      const float rG = sigm(gr), zG = sigm(gz);
      const float nG = tanh_((G[row][256 + dcol] + bihn1[dcol]) + rG * (G[row][384 + dcol] + bhhn1[dcol]));
      const float hn = (1.f - zG) * nG + zG * h1f[row][dcol];
      h1f[row][dcol] = hn;
      const unsigned short hb = f2bf(hn);
      h1b[row][dcol] = hb;
      rout[(size_t)(b0 + row) * (L_ * H_) + t * H_ + dcol] = hb;
    }
    __syncthreads();
  }
}

// ---------------------------------------------------------------------------
// Fused attention (both stacks) + delayed decoder. One block = one batch row b,
// one 64-row p-chunk. Pass 0: c1 rows [p0,p0+64); pass 1: c2 rows min(p+10,511).
// c1/c2 never hit HBM. new = [ctx | r] @ w_c^T as K=256 MFMA; w_c frags in regs.
// ---------------------------------------------------------------------------
__global__ __launch_bounds__(512, 2)
void attn_dec_kernel(
    const unsigned short* __restrict__ r1,
    const unsigned short* __restrict__ r2,
    const float* __restrict__ w_a,   // (1,256)
    const float* __restrict__ w_c,   // (128,256)
    const float* __restrict__ b_c,   // (128,)
    const float* __restrict__ w_o,   // (1,256)
    const float* __restrict__ b_o,   // (1,)
    float* __restrict__ out)         // (B*L,)
{
  const int bx = blockIdx.x;
  const int b  = bx >> 3;
  const int p0 = (bx & 7) * 64;
  const int tid = threadIdx.x, wave = tid >> 6, lane = tid & 63;
  const int lcol = lane & 15, lquad = lane >> 4;

  __shared__ __attribute__((aligned(16))) unsigned short rwin[69][H_ + 8];  // r window
  __shared__ __attribute__((aligned(16))) unsigned short ctxb[64][H_ + 8];  // softmax-weighted ctx
  __shared__ __attribute__((aligned(16))) unsigned short newb[64][H_ + 8];  // c rows (bf16)
  __shared__ float sp[69], sh[69];
  __shared__ float wgt[64][ATTN_];
  __shared__ float waS[256], wos[256], bcs[128];
  __shared__ float decacc[64];

  // w_c B-fragments: wave owns output N-tile `wave` (cols 16w..16w+15); K=256 -> 8 ksteps
  bf16x8 Wc[8];
  {
    const int n = 16 * wave + lcol;
#pragma unroll
    for (int ks = 0; ks < 8; ++ks) {
      const float* s = w_c + n * 256 + ks * 32 + lquad * 8;
      ushort8 u;
#pragma unroll
      for (int j = 0; j < 8; ++j) u[j] = f2bf(s[j]);
      Wc[ks] = __builtin_bit_cast(bf16x8, u);
    }
  }
  for (int i = tid; i < 256; i += 512) { waS[i] = w_a[i]; wos[i] = w_o[i]; }
  for (int i = tid; i < 128; i += 512) bcs[i] = b_c[i];

  for (int pass = 0; pass < 2; ++pass) {
    const unsigned short* rsrc = pass ? r2 : r1;
    const int wb = pass ? (p0 + 5) : (p0 - 5);   // global row of rwin[0]
    __syncthreads();
    // load r window (zero-fill out of range)
    for (int idx = tid; idx < 69 * H_; idx += 512) {
      const int rw = idx >> 7, c = idx & 127;
      const int g = wb + rw;
      rwin[rw][c] = (g >= 0 && g < L_) ? rsrc[(size_t)b * (L_ * H_) + g * H_ + c] : (unsigned short)0;
    }
    __syncthreads();
    // s_p, s_h per window row (8 lanes x 16 elems + shuffle reduce)
    for (int base = 0; base < 69; base += 64) {
      const int rw = base + (tid >> 3);
      if (rw < 69) {
        const int sub = tid & 7;
        float ap = 0.f, ah = 0.f;
        for (int e = 0; e < 16; ++e) {
          const float rv = bf2f(rwin[rw][sub * 16 + e]);
          ah += rv * waS[sub * 16 + e];
          ap += rv * waS[128 + sub * 16 + e];
        }
        ap += __shfl_xor(ap, 1); ap += __shfl_xor(ap, 2); ap += __shfl_xor(ap, 4);
        ah += __shfl_xor(ah, 1); ah += __shfl_xor(ah, 2); ah += __shfl_xor(ah, 4);
        if (sub == 0) { sp[rw] = ap; sh[rw] = ah; }
      }
    }
    __syncthreads();
    // softmax weights per output row (b_a is uniform -> cancels in softmax)
    if (tid < 64) {
      const int m = tid;
      int wq = m + 5;
      if (pass == 1) { const int over = p0 + DLY_ + m - (L_ - 1); if (over > 0) wq -= over; }
      float e[ATTN_], mx = -1e30f;
#pragma unroll
      for (int j = 0; j < ATTN_; ++j) { e[j] = sp[wq - 5 + j] + sh[wq]; mx = fmaxf(mx, e[j]); }
      float s = 0.f;
#pragma unroll
      for (int j = 0; j < ATTN_; ++j) { e[j] = __expf(e[j] - mx); s += e[j]; }
      const float inv = 1.f / s;
#pragma unroll
      for (int j = 0; j < ATTN_; ++j) wgt[m][j] = e[j] * inv;
    }
    __syncthreads();
    // ctx rows
    for (int idx = tid; idx < 64 * H_; idx += 512) {
      const int m = idx >> 7, c = idx & 127;
      int wq = m + 5;
      if (pass == 1) { const int over = p0 + DLY_ + m - (L_ - 1); if (over > 0) wq -= over; }
      float s = 0.f;
#pragma unroll
      for (int j = 0; j < ATTN_; ++j) s += wgt[m][j] * bf2f(rwin[wq - 5 + j][c]);
      ctxb[m][c] = f2bf(s);
    }
    __syncthreads();
    // MFMA: new = [ctx | r] @ w_c^T  (+ b_c)
#pragma unroll
    for (int mt = 0; mt < 4; ++mt) {
      const int m_ = mt * 16 + lcol;
      int wq = m_ + 5;
      if (pass == 1) { const int over = p0 + DLY_ + m_ - (L_ - 1); if (over > 0) wq -= over; }
      floatx4 acc = {0.f,0.f,0.f,0.f};
#pragma unroll
      for (int ks = 0; ks < 4; ++ks) {
        bf16x8 af = *(const bf16x8*)&ctxb[m_][ks * 32 + lquad * 8];
        acc = mfma16(af, Wc[ks], acc);
      }
#pragma unroll
      for (int ks = 4; ks < 8; ++ks) {
        bf16x8 af = *(const bf16x8*)&rwin[wq][(ks - 4) * 32 + lquad * 8];
        acc = mfma16(af, Wc[ks], acc);
      }
      const int col = 16 * wave + lcol;
#pragma unroll
      for (int j = 0; j < 4; ++j) {
        const int m2 = mt * 16 + lquad * 4 + j;
        newb[m2][col] = f2bf(acc[j] + bcs[col]);
      }
    }
    __syncthreads();
    // passthrough rows p<ATTN: c = r (no b_c)
    if (pass == 0 && p0 == 0) {
      for (int idx = tid; idx < ATTN_ * H_; idx += 512) {
        const int m = idx >> 7, c = idx & 127;
        newb[m][c] = rwin[m + 5][c];
      }
      __syncthreads();
    }
    // decoder partial: dot(new_row, w_o half)
    {
      const int m = tid >> 3, sub = tid & 7;
      float v = 0.f;
      for (int e = 0; e < 16; ++e) {
        const int k = sub * 16 + e;
        v += bf2f(newb[m][k]) * wos[pass * 128 + k];
      }
      v += __shfl_xor(v, 1); v += __shfl_xor(v, 2); v += __shfl_xor(v, 4);
      if (sub == 0) {
        if (pass == 0) decacc[m] = v;
        else out[(size_t)b * L_ + p0 + m] = sigm(decacc[m] + v + b_o[0]);
      }
    }
  }
}

extern "C" void kernel_launch(void* const* d_in, const int* in_sizes, int n_in,
                              void* d_out, int out_size, void* d_ws, size_t ws_size,
                              hipStream_t stream) {
  const float* recv   = (const float*)d_in[0];
  const float* wih1l0 = (const float*)d_in[1];
  const float* whh1l0 = (const float*)d_in[2];
  const float* bih1l0 = (const float*)d_in[3];
  const float* bhh1l0 = (const float*)d_in[4];
  const float* wih1l1 = (const float*)d_in[5];
  const float* whh1l1 = (const float*)d_in[6];
  const float* bih1l1 = (const float*)d_in[7];
  const float* bhh1l1 = (const float*)d_in[8];
  const float* wih2l0 = (const float*)d_in[9];
  const float* whh2l0 = (const float*)d_in[10];
  const float* bih2l0 = (const float*)d_in[11];
  const float* bhh2l0 = (const float*)d_in[12];
  const float* wih2l1 = (const float*)d_in[13];
  const float* whh2l1 = (const float*)d_in[14];
  const float* bih2l1 = (const float*)d_in[15];
  const float* bhh2l1 = (const float*)d_in[16];
  const float* w_a    = (const float*)d_in[17];
  const float* b_a    = (const float*)d_in[18]; (void)b_a; // uniform: cancels in softmax
  const float* w_c    = (const float*)d_in[19];
  const float* b_c    = (const float*)d_in[20];
  const float* w_o    = (const float*)d_in[21];
  const float* b_o    = (const float*)d_in[22];
  // d_in[23]=attn_num(5), d_in[24]=d_delay(10): compile-time constants here

  unsigned short* r1 = (unsigned short*)d_ws;                 // (B,L,H) bf16
  unsigned short* r2 = r1 + (size_t)B_ * L_ * H_;             // (B,L,H) bf16  (total 256 MiB)

  gru_stack_kernel<<<128, 512, 0, stream>>>(
      recv,
      wih1l0, whh1l0, bih1l0, bhh1l0, wih1l1, whh1l1, bih1l1, bhh1l1,
      wih2l0, whh2l0, bih2l0, bhh2l0, wih2l1, whh2l1, bih2l1, bhh2l1,
      r1, r2);

  attn_dec_kernel<<<B_ * (L_ / 64), 512, 0, stream>>>(
      r1, r2, w_a, w_c, b_c, w_o, b_o, (float*)d_out);
}

// Round 2
// 1711.563 us; speedup vs baseline: 1.2493x; 1.2493x over previous
//
#include <hip/hip_runtime.h>

// Problem constants (fixed by setup_inputs; attn_num=5, d_delay=10 are python ints)
#define B_    1024
#define L_    512
#define H_    128
#define TH_   384   // 3*H
#define NIN_  2
#define ATTN_ 5
#define DLY_  10

typedef __bf16 bf16x8 __attribute__((ext_vector_type(8)));
typedef unsigned short ushort8 __attribute__((ext_vector_type(8)));
typedef float floatx4 __attribute__((ext_vector_type(4)));

__device__ __forceinline__ unsigned short f2bf(float f) {
  unsigned int x = __builtin_bit_cast(unsigned int, f);
  x += 0x7fffu + ((x >> 16) & 1u);          // RNE
  return (unsigned short)(x >> 16);
}
__device__ __forceinline__ float bf2f(unsigned short u) {
  unsigned int x = ((unsigned int)u) << 16;
  return __builtin_bit_cast(float, x);
}
__device__ __forceinline__ float sigm(float x) { return 1.0f / (1.0f + __expf(-x)); }
__device__ __forceinline__ float tanh_(float x) {
  x = fminf(15.0f, fmaxf(-15.0f, x));
  float e = __expf(-2.0f * x);
  return (1.0f - e) / (1.0f + e);
}
__device__ __forceinline__ floatx4 mfma16(bf16x8 a, bf16x8 b, floatx4 c) {
  return __builtin_amdgcn_mfma_f32_16x16x32_bf16(a, b, c, 0, 0, 0);
}

// ---------------------------------------------------------------------------
// Fused 2-layer GRU, persistent over 512 steps. One block = 16 batch rows of
// one stack. 8 waves; wave w owns gate-dim tile [16w,16w+16) for ALL gates of
// BOTH layers. Elementwise GRU update done IN REGISTERS directly on the MFMA
// D-layout (row=lquad*4+reg is batch row, col=16w+lcol is gate dim) — no G
// matrix, no layout transpose, 2 barriers/step instead of 4.
// fp32 master h in registers (same lane computes & consumes); bf16 copy in
// LDS for the cross-wave A-fragment transpose. h0b double-buffered (phase A
// reads old h0 while writing new h0). recv prefetched in 64-step LDS chunks.
// rout (bf16) stores staged coalesced from h1b during next step's phase A.
// ---------------------------------------------------------------------------
__global__ __launch_bounds__(512, 2)
void gru_stack_kernel(
    const float* __restrict__ recv,
    const float* __restrict__ wih0_1, const float* __restrict__ whh0_1,
    const float* __restrict__ bih0_1, const float* __restrict__ bhh0_1,
    const float* __restrict__ wih1_1, const float* __restrict__ whh1_1,
    const float* __restrict__ bih1_1, const float* __restrict__ bhh1_1,
    const float* __restrict__ wih0_2, const float* __restrict__ whh0_2,
    const float* __restrict__ bih0_2, const float* __restrict__ bhh0_2,
    const float* __restrict__ wih1_2, const float* __restrict__ whh1_2,
    const float* __restrict__ bih1_2, const float* __restrict__ bhh1_2,
    unsigned short* __restrict__ r1, unsigned short* __restrict__ r2)
{
  const int bid  = blockIdx.x;        // 0..127
  const int stk  = bid >> 6;          // 0: stack1, 1: stack2
  const int b0   = (bid & 63) * 16;
  const int tid  = threadIdx.x;
  const int wave = tid >> 6;
  const int lane = tid & 63;
  const int lcol = lane & 15;
  const int lquad = lane >> 4;
  const int dim  = 16 * wave + lcol;  // gate dim this lane owns (D-layout col)

  const float* wih0 = stk ? wih0_2 : wih0_1;
  const float* whh0 = stk ? whh0_2 : whh0_1;
  const float* bih0 = stk ? bih0_2 : bih0_1;
  const float* bhh0 = stk ? bhh0_2 : bhh0_1;
  const float* wih1 = stk ? wih1_2 : wih1_1;
  const float* whh1 = stk ? whh1_2 : whh1_1;
  const float* bih1 = stk ? bih1_2 : bih1_1;
  const float* bhh1 = stk ? bhh1_2 : bhh1_1;
  unsigned short* rout = stk ? r2 : r1;

  __shared__ __attribute__((aligned(16))) unsigned short h0b[2][16][H_ + 8];
  __shared__ __attribute__((aligned(16))) unsigned short h1b[16][H_ + 8];
  __shared__ __attribute__((aligned(16))) float xs[16][132];   // 64-step input chunk

  // --- loop-invariant weight B-fragments in registers ---
  bf16x8 Whh0[3][4], Wih1[3][4], Whh1[3][4];
  {
#pragma unroll
    for (int ti = 0; ti < 3; ++ti) {
      const int g = ti * 128 + 16 * wave + lcol;   // B-frag n index = w row
#pragma unroll
      for (int ks = 0; ks < 4; ++ks) {
        const float* s0 = whh0 + g * H_ + ks * 32 + lquad * 8;
        const float* s1 = wih1 + g * H_ + ks * 32 + lquad * 8;
        const float* s2 = whh1 + g * H_ + ks * 32 + lquad * 8;
        ushort8 u0, u1, u2;
#pragma unroll
        for (int j = 0; j < 8; ++j) { u0[j] = f2bf(s0[j]); u1[j] = f2bf(s1[j]); u2[j] = f2bf(s2[j]); }
        Whh0[ti][ks] = __builtin_bit_cast(bf16x8, u0);
        Wih1[ti][ks] = __builtin_bit_cast(bf16x8, u1);
        Whh1[ti][ks] = __builtin_bit_cast(bf16x8, u2);
      }
    }
  }
  // --- per-lane loop-invariant scalars (layer0 input weights + all biases) ---
  const float wr0 = wih0[dim * 2],         wr1 = wih0[dim * 2 + 1];
  const float wz0 = wih0[(128 + dim) * 2], wz1 = wih0[(128 + dim) * 2 + 1];
  const float wn0 = wih0[(256 + dim) * 2], wn1 = wih0[(256 + dim) * 2 + 1];
  const float br0 = bih0[dim] + bhh0[dim];
  const float bz0 = bih0[128 + dim] + bhh0[128 + dim];
  const float bin0 = bih0[256 + dim], bhn0 = bhh0[256 + dim];
  const float br1 = bih1[dim] + bhh1[dim];
  const float bz1 = bih1[128 + dim] + bhh1[128 + dim];
  const float bin1 = bih1[256 + dim], bhn1 = bhh1[256 + dim];

  for (int i = tid; i < 2 * 16 * (H_ + 8); i += 512) ((unsigned short*)h0b)[i] = 0;
  for (int i = tid; i < 16 * (H_ + 8); i += 512) ((unsigned short*)h1b)[i] = 0;
  __syncthreads();

  float h0m[4] = {0.f, 0.f, 0.f, 0.f};   // fp32 master h, rows lquad*4+j, col dim
  float h1m[4] = {0.f, 0.f, 0.f, 0.f};
  // rout-staging mapping (coalesced): 32 threads per batch row, ushort4 each
  const int srow = tid >> 5;
  const int scol = (tid & 31) * 4;

  int buf = 0;  // h0b[buf] holds h0(t-1)
  floatx4 bR, bZ, bGh;   // layer1 accumulators, persist across the mid barrier

  for (int tb = 0; tb < L_; tb += 64) {
    // stage next 64 steps of input (coalesced float4)
    {
      const int row = tid >> 5, c4 = (tid & 31) * 4;
      const float4 v = *(const float4*)&recv[(size_t)(b0 + row) * (L_ * NIN_) + tb * NIN_ + c4];
      *(float4*)&xs[row][c4] = v;
    }
    __syncthreads();

    for (int tl = 0; tl < 64; ++tl) {
      const int t = tb + tl;
      // input values for this lane's 4 rows (LDS broadcast reads)
      float x0[4], x1[4];
#pragma unroll
      for (int j = 0; j < 4; ++j) {
        x0[j] = xs[lquad * 4 + j][2 * tl];
        x1[j] = xs[lquad * 4 + j][2 * tl + 1];
      }
      // stage rout store of h1(t-1) (read now, store below — hides under MFMA)
      ushort4 hprev = *(const ushort4*)&h1b[srow][scol];

      // ---- phase A: gh0 = h0_prev @ Whh0^T ; gh1 = h1_prev @ Whh1^T ----
      floatx4 aR = {0.f,0.f,0.f,0.f}, aZ = {0.f,0.f,0.f,0.f}, aN = {0.f,0.f,0.f,0.f};
      bR = (floatx4){0.f,0.f,0.f,0.f}; bZ = (floatx4){0.f,0.f,0.f,0.f}; bGh = (floatx4){0.f,0.f,0.f,0.f};
#pragma unroll
      for (int ks = 0; ks < 4; ++ks) {
        bf16x8 a0 = *(const bf16x8*)&h0b[buf][lcol][ks * 32 + lquad * 8];
        bf16x8 a1 = *(const bf16x8*)&h1b[lcol][ks * 32 + lquad * 8];
        aR = mfma16(a0, Whh0[0][ks], aR);
        aZ = mfma16(a0, Whh0[1][ks], aZ);
        aN = mfma16(a0, Whh0[2][ks], aN);
        bR = mfma16(a1, Whh1[0][ks], bR);
        bZ = mfma16(a1, Whh1[1][ks], bZ);
        bGh = mfma16(a1, Whh1[2][ks], bGh);
      }
      if (t > 0)
        *(ushort4*)&rout[(size_t)(b0 + srow) * (L_ * H_) + (size_t)(t - 1) * H_ + scol] = hprev;

      // ---- layer0 update, in registers ----
#pragma unroll
      for (int j = 0; j < 4; ++j) {
        const float gr = aR[j] + x0[j] * wr0 + x1[j] * wr1 + br0;
        const float gz = aZ[j] + x0[j] * wz0 + x1[j] * wz1 + bz0;
        const float rg = sigm(gr), zg = sigm(gz);
        const float ng = tanh_(x0[j] * wn0 + x1[j] * wn1 + bin0 + rg * (aN[j] + bhn0));
        h0m[j] = (1.f - zg) * ng + zg * h0m[j];
        h0b[buf ^ 1][lquad * 4 + j][dim] = f2bf(h0m[j]);
      }
      __syncthreads();

      // ---- phase B: += h0_new @ Wih1^T ; layer1 update ----
      floatx4 bGi = {0.f,0.f,0.f,0.f};
#pragma unroll
      for (int ks = 0; ks < 4; ++ks) {
        bf16x8 a0 = *(const bf16x8*)&h0b[buf ^ 1][lcol][ks * 32 + lquad * 8];
        bR = mfma16(a0, Wih1[0][ks], bR);
        bZ = mfma16(a0, Wih1[1][ks], bZ);
        bGi = mfma16(a0, Wih1[2][ks], bGi);
      }
#pragma unroll
      for (int j = 0; j < 4; ++j) {
        const float rg = sigm(bR[j] + br1), zg = sigm(bZ[j] + bz1);
        const float ng = tanh_(bGi[j] + bin1 + rg * (bGh[j] + bhn1));
        h1m[j] = (1.f - zg) * ng + zg * h1m[j];
        h1b[lquad * 4 + j][dim] = f2bf(h1m[j]);
      }
      __syncthreads();
      buf ^= 1;
    }
  }
  // epilogue: store h1(L-1)
  {
    const ushort4 v = *(const ushort4*)&h1b[srow][scol];
    *(ushort4*)&rout[(size_t)(b0 + srow) * (L_ * H_) + (size_t)(L_ - 1) * H_ + scol] = v;
  }
}

// ---------------------------------------------------------------------------
// Fused attention (both stacks) + delayed decoder. One block = one batch row b,
// one 64-row p-chunk. Pass 0: c1 rows [p0,p0+64); pass 1: c2 rows min(p+10,511).
// c1/c2 never hit HBM. new = [ctx | r] @ w_c^T as K=256 MFMA; w_c frags in regs.
// ---------------------------------------------------------------------------
__global__ __launch_bounds__(512, 2)
void attn_dec_kernel(
    const unsigned short* __restrict__ r1,
    const unsigned short* __restrict__ r2,
    const float* __restrict__ w_a,   // (1,256)
    const float* __restrict__ w_c,   // (128,256)
    const float* __restrict__ b_c,   // (128,)
    const float* __restrict__ w_o,   // (1,256)
    const float* __restrict__ b_o,   // (1,)
    float* __restrict__ out)         // (B*L,)
{
  const int bx = blockIdx.x;
  const int b  = bx >> 3;
  const int p0 = (bx & 7) * 64;
  const int tid = threadIdx.x, wave = tid >> 6, lane = tid & 63;
  const int lcol = lane & 15, lquad = lane >> 4;

  __shared__ __attribute__((aligned(16))) unsigned short rwin[69][H_ + 8];  // r window
  __shared__ __attribute__((aligned(16))) unsigned short ctxb[64][H_ + 8];  // softmax-weighted ctx
  __shared__ __attribute__((aligned(16))) unsigned short newb[64][H_ + 8];  // c rows (bf16)
  __shared__ float sp[69], sh[69];
  __shared__ float wgt[64][ATTN_];
  __shared__ float waS[256], wos[256], bcs[128];
  __shared__ float decacc[64];

  // w_c B-fragments: wave owns output N-tile `wave` (cols 16w..16w+15); K=256 -> 8 ksteps
  bf16x8 Wc[8];
  {
    const int n = 16 * wave + lcol;
#pragma unroll
    for (int ks = 0; ks < 8; ++ks) {
      const float* s = w_c + n * 256 + ks * 32 + lquad * 8;
      ushort8 u;
#pragma unroll
      for (int j = 0; j < 8; ++j) u[j] = f2bf(s[j]);
      Wc[ks] = __builtin_bit_cast(bf16x8, u);
    }
  }
  for (int i = tid; i < 256; i += 512) { waS[i] = w_a[i]; wos[i] = w_o[i]; }
  for (int i = tid; i < 128; i += 512) bcs[i] = b_c[i];

  for (int pass = 0; pass < 2; ++pass) {
    const unsigned short* rsrc = pass ? r2 : r1;
    const int wb = pass ? (p0 + 5) : (p0 - 5);   // global row of rwin[0]
    __syncthreads();
    // load r window, vectorized ushort8 (16B/lane), zero-fill out of range
    for (int idx = tid; idx < 69 * 16; idx += 512) {
      const int rw = idx >> 4, c8 = (idx & 15) * 8;
      const int g = wb + rw;
      ushort8 v = {0, 0, 0, 0, 0, 0, 0, 0};
      if (g >= 0 && g < L_) v = *(const ushort8*)&rsrc[(size_t)b * (L_ * H_) + (size_t)g * H_ + c8];
      *(ushort8*)&rwin[rw][c8] = v;
    }
    __syncthreads();
    // s_p, s_h per window row (8 lanes x 16 elems + shuffle reduce)
    for (int base = 0; base < 69; base += 64) {
      const int rw = base + (tid >> 3);
      if (rw < 69) {
        const int sub = tid & 7;
        float ap = 0.f, ah = 0.f;
        for (int e = 0; e < 16; ++e) {
          const float rv = bf2f(rwin[rw][sub * 16 + e]);
          ah += rv * waS[sub * 16 + e];
          ap += rv * waS[128 + sub * 16 + e];
        }
        ap += __shfl_xor(ap, 1); ap += __shfl_xor(ap, 2); ap += __shfl_xor(ap, 4);
        ah += __shfl_xor(ah, 1); ah += __shfl_xor(ah, 2); ah += __shfl_xor(ah, 4);
        if (sub == 0) { sp[rw] = ap; sh[rw] = ah; }
      }
    }
    __syncthreads();
    // softmax weights per output row (b_a is uniform -> cancels in softmax)
    if (tid < 64) {
      const int m = tid;
      int wq = m + 5;
      if (pass == 1) { const int over = p0 + DLY_ + m - (L_ - 1); if (over > 0) wq -= over; }
      float e[ATTN_], mx = -1e30f;
#pragma unroll
      for (int j = 0; j < ATTN_; ++j) { e[j] = sp[wq - 5 + j] + sh[wq]; mx = fmaxf(mx, e[j]); }
      float s = 0.f;
#pragma unroll
      for (int j = 0; j < ATTN_; ++j) { e[j] = __expf(e[j] - mx); s += e[j]; }
      const float inv = 1.f / s;
#pragma unroll
      for (int j = 0; j < ATTN_; ++j) wgt[m][j] = e[j] * inv;
    }
    __syncthreads();
    // ctx rows
    for (int idx = tid; idx < 64 * H_; idx += 512) {
      const int m = idx >> 7, c = idx & 127;
      int wq = m + 5;
      if (pass == 1) { const int over = p0 + DLY_ + m - (L_ - 1); if (over > 0) wq -= over; }
      float s = 0.f;
#pragma unroll
      for (int j = 0; j < ATTN_; ++j) s += wgt[m][j] * bf2f(rwin[wq - 5 + j][c]);
      ctxb[m][c] = f2bf(s);
    }
    __syncthreads();
    // MFMA: new = [ctx | r] @ w_c^T  (+ b_c)
#pragma unroll
    for (int mt = 0; mt < 4; ++mt) {
      const int m_ = mt * 16 + lcol;
      int wq = m_ + 5;
      if (pass == 1) { const int over = p0 + DLY_ + m_ - (L_ - 1); if (over > 0) wq -= over; }
      floatx4 acc = {0.f,0.f,0.f,0.f};
#pragma unroll
      for (int ks = 0; ks < 4; ++ks) {
        bf16x8 af = *(const bf16x8*)&ctxb[m_][ks * 32 + lquad * 8];
        acc = mfma16(af, Wc[ks], acc);
      }
#pragma unroll
      for (int ks = 4; ks < 8; ++ks) {
        bf16x8 af = *(const bf16x8*)&rwin[wq][(ks - 4) * 32 + lquad * 8];
        acc = mfma16(af, Wc[ks], acc);
      }
      const int col = 16 * wave + lcol;
#pragma unroll
      for (int j = 0; j < 4; ++j) {
        const int m2 = mt * 16 + lquad * 4 + j;
        newb[m2][col] = f2bf(acc[j] + bcs[col]);
      }
    }
    __syncthreads();
    // passthrough rows p<ATTN: c = r (no b_c)
    if (pass == 0 && p0 == 0) {
      for (int idx = tid; idx < ATTN_ * H_; idx += 512) {
        const int m = idx >> 7, c = idx & 127;
        newb[m][c] = rwin[m + 5][c];
      }
      __syncthreads();
    }
    // decoder partial: dot(new_row, w_o half)
    {
      const int m = tid >> 3, sub = tid & 7;
      float v = 0.f;
      for (int e = 0; e < 16; ++e) {
        const int k = sub * 16 + e;
        v += bf2f(newb[m][k]) * wos[pass * 128 + k];
      }
      v += __shfl_xor(v, 1); v += __shfl_xor(v, 2); v += __shfl_xor(v, 4);
      if (sub == 0) {
        if (pass == 0) decacc[m] = v;
        else out[(size_t)b * L_ + p0 + m] = sigm(decacc[m] + v + b_o[0]);
      }
    }
  }
}

extern "C" void kernel_launch(void* const* d_in, const int* in_sizes, int n_in,
                              void* d_out, int out_size, void* d_ws, size_t ws_size,
                              hipStream_t stream) {
  const float* recv   = (const float*)d_in[0];
  const float* wih1l0 = (const float*)d_in[1];
  const float* whh1l0 = (const float*)d_in[2];
  const float* bih1l0 = (const float*)d_in[3];
  const float* bhh1l0 = (const float*)d_in[4];
  const float* wih1l1 = (const float*)d_in[5];
  const float* whh1l1 = (const float*)d_in[6];
  const float* bih1l1 = (const float*)d_in[7];
  const float* bhh1l1 = (const float*)d_in[8];
  const float* wih2l0 = (const float*)d_in[9];
  const float* whh2l0 = (const float*)d_in[10];
  const float* bih2l0 = (const float*)d_in[11];
  const float* bhh2l0 = (const float*)d_in[12];
  const float* wih2l1 = (const float*)d_in[13];
  const float* whh2l1 = (const float*)d_in[14];
  const float* bih2l1 = (const float*)d_in[15];
  const float* bhh2l1 = (const float*)d_in[16];
  const float* w_a    = (const float*)d_in[17];
  const float* b_a    = (const float*)d_in[18]; (void)b_a; // uniform: cancels in softmax
  const float* w_c    = (const float*)d_in[19];
  const float* b_c    = (const float*)d_in[20];
  const float* w_o    = (const float*)d_in[21];
  const float* b_o    = (const float*)d_in[22];
  // d_in[23]=attn_num(5), d_in[24]=d_delay(10): compile-time constants here

  unsigned short* r1 = (unsigned short*)d_ws;                 // (B,L,H) bf16
  unsigned short* r2 = r1 + (size_t)B_ * L_ * H_;             // (B,L,H) bf16

  gru_stack_kernel<<<128, 512, 0, stream>>>(
      recv,
      wih1l0, whh1l0, bih1l0, bhh1l0, wih1l1, whh1l1, bih1l1, bhh1l1,
      wih2l0, whh2l0, bih2l0, bhh2l0, wih2l1, whh2l1, bih2l1, bhh2l1,
      r1, r2);

  attn_dec_kernel<<<B_ * (L_ / 64), 512, 0, stream>>>(
      r1, r2, w_a, w_c, b_c, w_o, b_o, (float*)d_out);
}

// Round 4
// 1128.737 us; speedup vs baseline: 1.8944x; 1.5164x over previous
//
#include <hip/hip_runtime.h>

// Problem constants (fixed by setup_inputs; attn_num=5, d_delay=10 are python ints)
#define B_    1024
#define L_    512
#define H_    128
#define TH_   384   // 3*H
#define NIN_  2
#define ATTN_ 5
#define DLY_  10

typedef __bf16 bf16x8 __attribute__((ext_vector_type(8)));
typedef unsigned short ushort8 __attribute__((ext_vector_type(8)));
typedef float floatx4 __attribute__((ext_vector_type(4)));

__device__ __forceinline__ unsigned short f2bf(float f) {
  unsigned int x = __builtin_bit_cast(unsigned int, f);
  x += 0x7fffu + ((x >> 16) & 1u);          // RNE
  return (unsigned short)(x >> 16);
}
__device__ __forceinline__ float bf2f(unsigned short u) {
  unsigned int x = ((unsigned int)u) << 16;
  return __builtin_bit_cast(float, x);
}
__device__ __forceinline__ float sigm(float x) { return 1.0f / (1.0f + __expf(-x)); }
// Pre-scaled sigmoid: y = -log2(e)*x already -> sigma(x) = rcp(1+exp2(y)).
__device__ __forceinline__ float sigp(float y) {
  return __builtin_amdgcn_rcpf(1.0f + __builtin_amdgcn_exp2f(y));
}
__device__ __forceinline__ floatx4 mfma16(bf16x8 a, bf16x8 b, floatx4 c) {
  return __builtin_amdgcn_mfma_f32_16x16x32_bf16(a, b, c, 0, 0, 0);
}

// Swizzled LDS layout for h matrices (ushort units):
//   hoff(r,d) = r*136 + ((d + ((r&8)<<1)) & 127)
// Row stride 136 > 128 -> rows PROVABLY disjoint (Round-3 bug: base-offset
// swizzle overlapped rows 3/4, 7/8, 11/12). Column rotation by 16 for rows
// 8..15 makes the gate-dim b16 scatter (quads write rows {j,4+j,8+j,12+j})
// hit dword-bank bases {0,16,8,24}+const mod 32 -> all 32 banks tiled,
// 2 lanes/dword = free. Rotation is a multiple of 16 so 8-elem A-fragment
// runs stay contiguous and 16B-aligned (no wrap straddle: 8 | 128, 16 | 128).
__device__ __forceinline__ int hoff(int r, int d) {
  return r * 136 + ((d + ((r & 8) << 1)) & 127);
}

// ---------------------------------------------------------------------------
// Fused 2-layer GRU, persistent over 512 steps, SINGLE barrier per step.
// Layer1 runs one step behind layer0: iteration i computes layer0 step t=i
// (from h0(i-1), x(i)) and layer1 step t=i-1 (from h0(i-1), h1(i-2)) — all
// MFMA inputs available simultaneously -> one MFMA phase, one LDS write
// turnaround, one __syncthreads per step.
// Elementwise GRU update in registers on the MFMA D-layout. Weights pre-scaled
// by -log2(e) (r,z) / -2*log2(e) (n) so sigma/tanh = rcp(1+exp2(.)).
// Output h1(t) staged per-thread into an LDS ring (obuf) and flushed as 8
// coalesced global stores every 8 steps — amortizes the vmcnt(0) barrier
// drain that serialized an HBM store into every step of Round 2.
// ---------------------------------------------------------------------------
__global__ __launch_bounds__(512, 2)
void gru_stack_kernel(
    const float* __restrict__ recv,
    const float* __restrict__ wih0_1, const float* __restrict__ whh0_1,
    const float* __restrict__ bih0_1, const float* __restrict__ bhh0_1,
    const float* __restrict__ wih1_1, const float* __restrict__ whh1_1,
    const float* __restrict__ bih1_1, const float* __restrict__ bhh1_1,
    const float* __restrict__ wih0_2, const float* __restrict__ whh0_2,
    const float* __restrict__ bih0_2, const float* __restrict__ bhh0_2,
    const float* __restrict__ wih1_2, const float* __restrict__ whh1_2,
    const float* __restrict__ bih1_2, const float* __restrict__ bhh1_2,
    unsigned short* __restrict__ r1, unsigned short* __restrict__ r2)
{
  const int bid  = blockIdx.x;        // 0..127
  const int stk  = bid >> 6;          // 0: stack1, 1: stack2
  const int b0   = (bid & 63) * 16;
  const int tid  = threadIdx.x;
  const int wave = tid >> 6;
  const int lane = tid & 63;
  const int lcol = lane & 15;
  const int lquad = lane >> 4;
  const int dim  = 16 * wave + lcol;  // gate dim this lane owns (D-layout col)

  const float* wih0 = stk ? wih0_2 : wih0_1;
  const float* whh0 = stk ? whh0_2 : whh0_1;
  const float* bih0 = stk ? bih0_2 : bih0_1;
  const float* bhh0 = stk ? bhh0_2 : bhh0_1;
  const float* wih1 = stk ? wih1_2 : wih1_1;
  const float* whh1 = stk ? whh1_2 : whh1_1;
  const float* bih1 = stk ? bih1_2 : bih1_1;
  const float* bhh1 = stk ? bhh1_2 : bhh1_1;
  unsigned short* rout = stk ? r2 : r1;

  __shared__ __attribute__((aligned(16))) unsigned short h0L[2][2176];  // swizzled, dbuf
  __shared__ __attribute__((aligned(16))) unsigned short h1L[2][2176];
  __shared__ __attribute__((aligned(16))) float xs[16][132];            // 64-step input chunk
  __shared__ __attribute__((aligned(16))) unsigned short obuf[8][16][H_]; // output ring

  const float S1 = -1.4426950408889634f;   // -log2(e)   (r,z gates)
  const float S2 = -2.8853900817779268f;   // -2*log2(e) (n gate)

  // --- loop-invariant weight B-fragments in registers (pre-scaled) ---
  bf16x8 Whh0[3][4], Wih1[3][4], Whh1[3][4];
  {
#pragma unroll
    for (int ti = 0; ti < 3; ++ti) {
      const float sc = (ti == 2) ? S2 : S1;
      const int g = ti * 128 + dim;   // B-frag n index
#pragma unroll
      for (int ks = 0; ks < 4; ++ks) {
        const float* s0 = whh0 + g * H_ + ks * 32 + lquad * 8;
        const float* s1 = wih1 + g * H_ + ks * 32 + lquad * 8;
        const float* s2 = whh1 + g * H_ + ks * 32 + lquad * 8;
        ushort8 u0, u1, u2;
#pragma unroll
        for (int j = 0; j < 8; ++j) {
          u0[j] = f2bf(s0[j] * sc); u1[j] = f2bf(s1[j] * sc); u2[j] = f2bf(s2[j] * sc);
        }
        Whh0[ti][ks] = __builtin_bit_cast(bf16x8, u0);
        Wih1[ti][ks] = __builtin_bit_cast(bf16x8, u1);
        Whh1[ti][ks] = __builtin_bit_cast(bf16x8, u2);
      }
    }
  }
  // --- per-lane loop-invariant scalars (pre-scaled) ---
  const float wr0 = wih0[dim * 2] * S1,         wr1 = wih0[dim * 2 + 1] * S1;
  const float wz0 = wih0[(128 + dim) * 2] * S1, wz1 = wih0[(128 + dim) * 2 + 1] * S1;
  const float wn0 = wih0[(256 + dim) * 2] * S2, wn1 = wih0[(256 + dim) * 2 + 1] * S2;
  const float br0 = (bih0[dim] + bhh0[dim]) * S1;
  const float bz0 = (bih0[128 + dim] + bhh0[128 + dim]) * S1;
  const float bin0 = bih0[256 + dim] * S2, bhn0 = bhh0[256 + dim] * S2;
  const float br1 = (bih1[dim] + bhh1[dim]) * S1;
  const float bz1 = (bih1[128 + dim] + bhh1[128 + dim]) * S1;
  const float bin1 = bih1[256 + dim] * S2, bhn1 = bhh1[256 + dim] * S2;

  for (int i = tid; i < 2 * 2176; i += 512) { ((unsigned short*)h0L)[i] = 0; ((unsigned short*)h1L)[i] = 0; }
  __syncthreads();

  float h0m[4] = {0.f, 0.f, 0.f, 0.f};   // fp32 master h, rows lquad*4+j, col dim
  float h1m[4] = {0.f, 0.f, 0.f, 0.f};

  // staging/store mapping (coalesced): 32 threads per batch row, ushort4 each
  const int srow = tid >> 5;
  const int scol = (tid & 31) * 4;
  const int hstage = hoff(srow, scol);
  const size_t routbase = (size_t)(b0 + srow) * (L_ * H_) + scol;
  // A-fragment read addressing: row lcol, element e=ks*32+lquad*8
  const int hAbase = lcol * 136;
  int aofs[4];
#pragma unroll
  for (int ks = 0; ks < 4; ++ks)
    aofs[ks] = ((ks * 32 + lquad * 8 + ((lcol & 8) << 1)) & 127);
  int wofs[4];
#pragma unroll
  for (int j = 0; j < 4; ++j) wofs[j] = hoff(lquad * 4 + j, dim);

#pragma unroll 2
  for (int i = 0; i < L_; ++i) {
    const int rb = i & 1, wb = rb ^ 1;
    if ((i & 63) == 0) {               // stage next 64 steps of input
      const float4 v = *(const float4*)&recv[(size_t)(b0 + srow) * (L_ * NIN_) + i * NIN_ + scol];
      *(float4*)&xs[srow][scol] = v;
      __syncthreads();
    }
    // flush ring (t = i-10 .. i-3) BEFORE this iter's copy overwrites slot 0
    if (i >= 10 && ((i - 2) & 7) == 0) {
#pragma unroll
      for (int s = 0; s < 8; ++s) {
        const ushort4 v = *(const ushort4*)&obuf[s][srow][scol];
        *(ushort4*)&rout[routbase + (size_t)(i - 10 + s) * H_] = v;
      }
    }
    // stage h1(i-2) (in read buffer) into ring slot (i-2)&7 (thread-local)
    if (i >= 2) {
      const ushort4 v = *(const ushort4*)&h1L[rb][hstage];
      *(ushort4*)&obuf[(i - 2) & 7][srow][scol] = v;
    }

    // ---- single MFMA phase: layer0 t=i and layer1 t=i-1 gates ----
    floatx4 aR = {0.f,0.f,0.f,0.f}, aZ = {0.f,0.f,0.f,0.f}, aN = {0.f,0.f,0.f,0.f};
    floatx4 bR = {0.f,0.f,0.f,0.f}, bZ = {0.f,0.f,0.f,0.f};
    floatx4 bGi = {0.f,0.f,0.f,0.f}, bGh = {0.f,0.f,0.f,0.f};
#pragma unroll
    for (int ks = 0; ks < 4; ++ks) {
      bf16x8 a0 = *(const bf16x8*)&h0L[rb][hAbase + aofs[ks]];  // h0(i-1)
      bf16x8 a1 = *(const bf16x8*)&h1L[rb][hAbase + aofs[ks]];  // h1(i-2)
      aR  = mfma16(a0, Whh0[0][ks], aR);
      aZ  = mfma16(a0, Whh0[1][ks], aZ);
      aN  = mfma16(a0, Whh0[2][ks], aN);
      bR  = mfma16(a0, Wih1[0][ks], bR);
      bZ  = mfma16(a0, Wih1[1][ks], bZ);
      bGi = mfma16(a0, Wih1[2][ks], bGi);
      bR  = mfma16(a1, Whh1[0][ks], bR);
      bZ  = mfma16(a1, Whh1[1][ks], bZ);
      bGh = mfma16(a1, Whh1[2][ks], bGh);
    }
    const int tl = i & 63;
    // ---- layer0 update (t=i), in registers ----
#pragma unroll
    for (int j = 0; j < 4; ++j) {
      const float2 xv = *(const float2*)&xs[lquad * 4 + j][2 * tl];
      const float rg = sigp(fmaf(xv.x, wr0, fmaf(xv.y, wr1, aR[j] + br0)));
      const float zg = sigp(fmaf(xv.x, wz0, fmaf(xv.y, wz1, aZ[j] + bz0)));
      const float ng = fmaf(2.f, sigp(fmaf(rg, aN[j] + bhn0,
                            fmaf(xv.x, wn0, fmaf(xv.y, wn1, bin0)))), -1.f);
      h0m[j] = fmaf(zg, h0m[j] - ng, ng);
      h0L[wb][wofs[j]] = f2bf(h0m[j]);
    }
    // ---- layer1 update (t=i-1), in registers ----
    if (i > 0) {
#pragma unroll
      for (int j = 0; j < 4; ++j) {
        const float rg = sigp(bR[j] + br1);
        const float zg = sigp(bZ[j] + bz1);
        const float ng = fmaf(2.f, sigp(fmaf(rg, bGh[j] + bhn1, bGi[j] + bin1)), -1.f);
        h1m[j] = fmaf(zg, h1m[j] - ng, ng);
        h1L[wb][wofs[j]] = f2bf(h1m[j]);
      }
    }
    __syncthreads();
  }

  // ---- tail iteration i=512: layer1 t=511 only ----
  {
    const ushort4 v = *(const ushort4*)&h1L[0][hstage];   // h1(510), slot 6
    *(ushort4*)&obuf[6][srow][scol] = v;
    floatx4 bR = {0.f,0.f,0.f,0.f}, bZ = {0.f,0.f,0.f,0.f};
    floatx4 bGi = {0.f,0.f,0.f,0.f}, bGh = {0.f,0.f,0.f,0.f};
#pragma unroll
    for (int ks = 0; ks < 4; ++ks) {
      bf16x8 a0 = *(const bf16x8*)&h0L[0][hAbase + aofs[ks]];   // h0(511)
      bf16x8 a1 = *(const bf16x8*)&h1L[0][hAbase + aofs[ks]];   // h1(510)
      bR  = mfma16(a0, Wih1[0][ks], bR);
      bZ  = mfma16(a0, Wih1[1][ks], bZ);
      bGi = mfma16(a0, Wih1[2][ks], bGi);
      bR  = mfma16(a1, Whh1[0][ks], bR);
      bZ  = mfma16(a1, Whh1[1][ks], bZ);
      bGh = mfma16(a1, Whh1[2][ks], bGh);
    }
#pragma unroll
    for (int j = 0; j < 4; ++j) {
      const float rg = sigp(bR[j] + br1);
      const float zg = sigp(bZ[j] + bz1);
      const float ng = fmaf(2.f, sigp(fmaf(rg, bGh[j] + bhn1, bGi[j] + bin1)), -1.f);
      h1m[j] = fmaf(zg, h1m[j] - ng, ng);
      h1L[1][wofs[j]] = f2bf(h1m[j]);
    }
    __syncthreads();
  }
  // ---- epilogue: t=504..510 from ring, t=511 from h1L[1] ----
#pragma unroll
  for (int s = 0; s < 7; ++s) {
    const ushort4 v = *(const ushort4*)&obuf[s][srow][scol];
    *(ushort4*)&rout[routbase + (size_t)(504 + s) * H_] = v;
  }
  {
    const ushort4 v = *(const ushort4*)&h1L[1][hstage];
    *(ushort4*)&rout[routbase + (size_t)(L_ - 1) * H_] = v;
  }
}

// ---------------------------------------------------------------------------
// Fused attention (both stacks) + delayed decoder. One block = one batch row b,
// one 64-row p-chunk. Pass 0: c1 rows [p0,p0+64); pass 1: c2 rows min(p+10,511).
// c1/c2 never hit HBM. new = [ctx | r] @ w_c^T as K=256 MFMA; w_c frags in regs.
// ---------------------------------------------------------------------------
__global__ __launch_bounds__(512, 2)
void attn_dec_kernel(
    const unsigned short* __restrict__ r1,
    const unsigned short* __restrict__ r2,
    const float* __restrict__ w_a,   // (1,256)
    const float* __restrict__ w_c,   // (128,256)
    const float* __restrict__ b_c,   // (128,)
    const float* __restrict__ w_o,   // (1,256)
    const float* __restrict__ b_o,   // (1,)
    float* __restrict__ out)         // (B*L,)
{
  const int bx = blockIdx.x;
  const int b  = bx >> 3;
  const int p0 = (bx & 7) * 64;
  const int tid = threadIdx.x, wave = tid >> 6, lane = tid & 63;
  const int lcol = lane & 15, lquad = lane >> 4;

  __shared__ __attribute__((aligned(16))) unsigned short rwin[69][H_ + 8];  // r window
  __shared__ __attribute__((aligned(16))) unsigned short ctxb[64][H_ + 8];  // softmax-weighted ctx
  __shared__ __attribute__((aligned(16))) unsigned short newb[64][H_ + 8];  // c rows (bf16)
  __shared__ float sp[69], sh[69];
  __shared__ float wgt[64][ATTN_];
  __shared__ float waS[256], wos[256], bcs[128];
  __shared__ float decacc[64];

  // w_c B-fragments: wave owns output N-tile `wave` (cols 16w..16w+15); K=256 -> 8 ksteps
  bf16x8 Wc[8];
  {
    const int n = 16 * wave + lcol;
#pragma unroll
    for (int ks = 0; ks < 8; ++ks) {
      const float* s = w_c + n * 256 + ks * 32 + lquad * 8;
      ushort8 u;
#pragma unroll
      for (int j = 0; j < 8; ++j) u[j] = f2bf(s[j]);
      Wc[ks] = __builtin_bit_cast(bf16x8, u);
    }
  }
  for (int i = tid; i < 256; i += 512) { waS[i] = w_a[i]; wos[i] = w_o[i]; }
  for (int i = tid; i < 128; i += 512) bcs[i] = b_c[i];

  for (int pass = 0; pass < 2; ++pass) {
    const unsigned short* rsrc = pass ? r2 : r1;
    const int wb = pass ? (p0 + 5) : (p0 - 5);   // global row of rwin[0]
    __syncthreads();
    // load r window, vectorized ushort8 (16B/lane), zero-fill out of range
    for (int idx = tid; idx < 69 * 16; idx += 512) {
      const int rw = idx >> 4, c8 = (idx & 15) * 8;
      const int g = wb + rw;
      ushort8 v = {0, 0, 0, 0, 0, 0, 0, 0};
      if (g >= 0 && g < L_) v = *(const ushort8*)&rsrc[(size_t)b * (L_ * H_) + (size_t)g * H_ + c8];
      *(ushort8*)&rwin[rw][c8] = v;
    }
    __syncthreads();
    // s_p, s_h per window row (8 lanes x 16 elems + shuffle reduce)
    for (int base = 0; base < 69; base += 64) {
      const int rw = base + (tid >> 3);
      if (rw < 69) {
        const int sub = tid & 7;
        float ap = 0.f, ah = 0.f;
        for (int e = 0; e < 16; ++e) {
          const float rv = bf2f(rwin[rw][sub * 16 + e]);
          ah += rv * waS[sub * 16 + e];
          ap += rv * waS[128 + sub * 16 + e];
        }
        ap += __shfl_xor(ap, 1); ap += __shfl_xor(ap, 2); ap += __shfl_xor(ap, 4);
        ah += __shfl_xor(ah, 1); ah += __shfl_xor(ah, 2); ah += __shfl_xor(ah, 4);
        if (sub == 0) { sp[rw] = ap; sh[rw] = ah; }
      }
    }
    __syncthreads();
    // softmax weights per output row (b_a is uniform -> cancels in softmax)
    if (tid < 64) {
      const int m = tid;
      int wq = m + 5;
      if (pass == 1) { const int over = p0 + DLY_ + m - (L_ - 1); if (over > 0) wq -= over; }
      float e[ATTN_], mx = -1e30f;
#pragma unroll
      for (int j = 0; j < ATTN_; ++j) { e[j] = sp[wq - 5 + j] + sh[wq]; mx = fmaxf(mx, e[j]); }
      float s = 0.f;
#pragma unroll
      for (int j = 0; j < ATTN_; ++j) { e[j] = __expf(e[j] - mx); s += e[j]; }
      const float inv = 1.f / s;
#pragma unroll
      for (int j = 0; j < ATTN_; ++j) wgt[m][j] = e[j] * inv;
    }
    __syncthreads();
    // ctx rows
    for (int idx = tid; idx < 64 * H_; idx += 512) {
      const int m = idx >> 7, c = idx & 127;
      int wq = m + 5;
      if (pass == 1) { const int over = p0 + DLY_ + m - (L_ - 1); if (over > 0) wq -= over; }
      float s = 0.f;
#pragma unroll
      for (int j = 0; j < ATTN_; ++j) s += wgt[m][j] * bf2f(rwin[wq - 5 + j][c]);
      ctxb[m][c] = f2bf(s);
    }
    __syncthreads();
    // MFMA: new = [ctx | r] @ w_c^T  (+ b_c)
#pragma unroll
    for (int mt = 0; mt < 4; ++mt) {
      const int m_ = mt * 16 + lcol;
      int wq = m_ + 5;
      if (pass == 1) { const int over = p0 + DLY_ + m_ - (L_ - 1); if (over > 0) wq -= over; }
      floatx4 acc = {0.f,0.f,0.f,0.f};
#pragma unroll
      for (int ks = 0; ks < 4; ++ks) {
        bf16x8 af = *(const bf16x8*)&ctxb[m_][ks * 32 + lquad * 8];
        acc = mfma16(af, Wc[ks], acc);
      }
#pragma unroll
      for (int ks = 4; ks < 8; ++ks) {
        bf16x8 af = *(const bf16x8*)&rwin[wq][(ks - 4) * 32 + lquad * 8];
        acc = mfma16(af, Wc[ks], acc);
      }
      const int col = 16 * wave + lcol;
#pragma unroll
      for (int j = 0; j < 4; ++j) {
        const int m2 = mt * 16 + lquad * 4 + j;
        newb[m2][col] = f2bf(acc[j] + bcs[col]);
      }
    }
    __syncthreads();
    // passthrough rows p<ATTN: c = r (no b_c)
    if (pass == 0 && p0 == 0) {
      for (int idx = tid; idx < ATTN_ * H_; idx += 512) {
        const int m = idx >> 7, c = idx & 127;
        newb[m][c] = rwin[m + 5][c];
      }
      __syncthreads();
    }
    // decoder partial: dot(new_row, w_o half)
    {
      const int m = tid >> 3, sub = tid & 7;
      float v = 0.f;
      for (int e = 0; e < 16; ++e) {
        const int k = sub * 16 + e;
        v += bf2f(newb[m][k]) * wos[pass * 128 + k];
      }
      v += __shfl_xor(v, 1); v += __shfl_xor(v, 2); v += __shfl_xor(v, 4);
      if (sub == 0) {
        if (pass == 0) decacc[m] = v;
        else out[(size_t)b * L_ + p0 + m] = sigm(decacc[m] + v + b_o[0]);
      }
    }
  }
}

extern "C" void kernel_launch(void* const* d_in, const int* in_sizes, int n_in,
                              void* d_out, int out_size, void* d_ws, size_t ws_size,
                              hipStream_t stream) {
  const float* recv   = (const float*)d_in[0];
  const float* wih1l0 = (const float*)d_in[1];
  const float* whh1l0 = (const float*)d_in[2];
  const float* bih1l0 = (const float*)d_in[3];
  const float* bhh1l0 = (const float*)d_in[4];
  const float* wih1l1 = (const float*)d_in[5];
  const float* whh1l1 = (const float*)d_in[6];
  const float* bih1l1 = (const float*)d_in[7];
  const float* bhh1l1 = (const float*)d_in[8];
  const float* wih2l0 = (const float*)d_in[9];
  const float* whh2l0 = (const float*)d_in[10];
  const float* bih2l0 = (const float*)d_in[11];
  const float* bhh2l0 = (const float*)d_in[12];
  const float* wih2l1 = (const float*)d_in[13];
  const float* whh2l1 = (const float*)d_in[14];
  const float* bih2l1 = (const float*)d_in[15];
  const float* bhh2l1 = (const float*)d_in[16];
  const float* w_a    = (const float*)d_in[17];
  const float* b_a    = (const float*)d_in[18]; (void)b_a; // uniform: cancels in softmax
  const float* w_c    = (const float*)d_in[19];
  const float* b_c    = (const float*)d_in[20];
  const float* w_o    = (const float*)d_in[21];
  const float* b_o    = (const float*)d_in[22];
  // d_in[23]=attn_num(5), d_in[24]=d_delay(10): compile-time constants here

  unsigned short* r1 = (unsigned short*)d_ws;                 // (B,L,H) bf16
  unsigned short* r2 = r1 + (size_t)B_ * L_ * H_;             // (B,L,H) bf16

  gru_stack_kernel<<<128, 512, 0, stream>>>(
      recv,
      wih1l0, whh1l0, bih1l0, bhh1l0, wih1l1, whh1l1, bih1l1, bhh1l1,
      wih2l0, whh2l0, bih2l0, bhh2l0, wih2l1, whh2l1, bih2l1, bhh2l1,
      r1, r2);

  attn_dec_kernel<<<B_ * (L_ / 64), 512, 0, stream>>>(
      r1, r2, w_a, w_c, b_c, w_o, b_o, (float*)d_out);
}

// Round 5
// 851.537 us; speedup vs baseline: 2.5111x; 1.3255x over previous
//
#include <hip/hip_runtime.h>

// Problem constants (fixed by setup_inputs; attn_num=5, d_delay=10 are python ints)
#define B_    1024
#define L_    512
#define H_    128
#define NIN_  2
#define ATTN_ 5
#define DLY_  10

typedef __bf16 bf16x8 __attribute__((ext_vector_type(8)));
typedef unsigned short ushort8 __attribute__((ext_vector_type(8)));
typedef float floatx4 __attribute__((ext_vector_type(4)));

__device__ __forceinline__ unsigned short f2bf(float f) {
  unsigned int x = __builtin_bit_cast(unsigned int, f);
  x += 0x7fffu + ((x >> 16) & 1u);          // RNE
  return (unsigned short)(x >> 16);
}
__device__ __forceinline__ float sigm(float x) { return 1.0f / (1.0f + __expf(-x)); }
// Pre-scaled sigmoid: y = -log2(e)*x already -> sigma(x) = rcp(1+exp2(y)).
__device__ __forceinline__ float sigp(float y) {
  return __builtin_amdgcn_rcpf(1.0f + __builtin_amdgcn_exp2f(y));
}
__device__ __forceinline__ floatx4 mfma16(bf16x8 a, bf16x8 b, floatx4 c) {
  return __builtin_amdgcn_mfma_f32_16x16x32_bf16(a, b, c, 0, 0, 0);
}

// Swizzled LDS layout for h matrices (ushort units): rows disjoint (stride
// 136 > 128); column rotation by 16 for rows 8..15 tiles the gate-dim b16
// scatter across all 32 banks (2 lanes/dword = free). Rotation is a multiple
// of 16 so 8/16-elem reads stay contiguous and 16B-aligned.
__device__ __forceinline__ int hoff(int r, int d) {
  return r * 136 + ((d + ((r & 8) << 1)) & 127);
}

// ---------------------------------------------------------------------------
// Fully-fused: 2-layer GRU + local attention + decoder partials, persistent
// over 512 steps, one barrier per step. One block = 16 batch rows of one stack.
//
// Pipeline at iteration i:
//   layer0 t=i   (h0(i-1), x(i))            all 8 waves, 9 MFMAs x 4 ksteps
//   layer1 t=i-1 (h0(i-1)->acc, h1(i-2))
//   dots  tau=i-2: wave0 MFMA h1(tau)[16x128] @ [wa_p|u1|u2|wo] -> 4 scalars/row
//   attn+dec p=i-3: wave1 lanes<16: softmax over s_p ring (s_h & b_a cancel),
//                   dec[p] = sum_j w_j q1[p-5+j] + q2[p] + b_c.wo  (p>=5)
//                   dec[p] = q0[p]                                  (p<5)
// where u1 = w_c[:, :H]^T wo_half, u2 = w_c[:, H:]^T wo_half (attention+
// decoder are linear after softmax -> collapse to per-row scalars; r1/r2
// never hit HBM). dec partials burst-stored every 8 steps; final tiny kernel
// applies delay + sigmoid.
// ---------------------------------------------------------------------------
__global__ __launch_bounds__(512, 2)
void gru_stack_kernel(
    const float* __restrict__ recv,
    const float* __restrict__ wih0_1, const float* __restrict__ whh0_1,
    const float* __restrict__ bih0_1, const float* __restrict__ bhh0_1,
    const float* __restrict__ wih1_1, const float* __restrict__ whh1_1,
    const float* __restrict__ bih1_1, const float* __restrict__ bhh1_1,
    const float* __restrict__ wih0_2, const float* __restrict__ whh0_2,
    const float* __restrict__ bih0_2, const float* __restrict__ bhh0_2,
    const float* __restrict__ wih1_2, const float* __restrict__ whh1_2,
    const float* __restrict__ bih1_2, const float* __restrict__ bhh1_2,
    const float* __restrict__ w_a, const float* __restrict__ w_c,
    const float* __restrict__ b_c, const float* __restrict__ w_o,
    float* __restrict__ dec1, float* __restrict__ dec2)
{
  const int bid  = blockIdx.x;        // 0..127
  const int stk  = bid >> 6;          // 0: stack1, 1: stack2
  const int b0   = (bid & 63) * 16;
  const int tid  = threadIdx.x;
  const int wave = tid >> 6;
  const int lane = tid & 63;
  const int lcol = lane & 15;
  const int lquad = lane >> 4;
  const int dim  = 16 * wave + lcol;  // gate dim this lane owns (D-layout col)

  const float* wih0 = stk ? wih0_2 : wih0_1;
  const float* whh0 = stk ? whh0_2 : whh0_1;
  const float* bih0 = stk ? bih0_2 : bih0_1;
  const float* bhh0 = stk ? bhh0_2 : bhh0_1;
  const float* wih1 = stk ? wih1_2 : wih1_1;
  const float* whh1 = stk ? whh1_2 : whh1_1;
  const float* bih1 = stk ? bih1_2 : bih1_1;
  const float* bhh1 = stk ? bhh1_2 : bhh1_1;
  float* dout = stk ? dec2 : dec1;

  __shared__ __attribute__((aligned(16))) unsigned short h0L[2][2176];  // swizzled, dbuf
  __shared__ __attribute__((aligned(16))) unsigned short h1L[2][2176];
  __shared__ __attribute__((aligned(16))) float xs[16][132];            // 64-step input chunk
  __shared__ __attribute__((aligned(16))) float SR[4][8][16];  // rings: s_p,q1,q2,q0
  __shared__ __attribute__((aligned(16))) float decring[16][8];
  __shared__ float waL[256];   // w_a
  __shared__ float woL[128];   // wo half for this stack
  __shared__ float uL[256];    // u1 | u2
  __shared__ float red[128];
  __shared__ float CcL;

  const float S1 = -1.4426950408889634f;   // -log2(e)   (r,z gates)
  const float S2 = -2.8853900817779268f;   // -2*log2(e) (n gate)

  // --- loop-invariant weight B-fragments in registers (pre-scaled) ---
  bf16x8 Whh0[3][4], Wih1[3][4], Whh1[3][4];
  {
#pragma unroll
    for (int ti = 0; ti < 3; ++ti) {
      const float sc = (ti == 2) ? S2 : S1;
      const int g = ti * 128 + dim;   // B-frag n index
#pragma unroll
      for (int ks = 0; ks < 4; ++ks) {
        const float* s0 = whh0 + g * H_ + ks * 32 + lquad * 8;
        const float* s1 = wih1 + g * H_ + ks * 32 + lquad * 8;
        const float* s2 = whh1 + g * H_ + ks * 32 + lquad * 8;
        ushort8 u0, u1, u2;
#pragma unroll
        for (int j = 0; j < 8; ++j) {
          u0[j] = f2bf(s0[j] * sc); u1[j] = f2bf(s1[j] * sc); u2[j] = f2bf(s2[j] * sc);
        }
        Whh0[ti][ks] = __builtin_bit_cast(bf16x8, u0);
        Wih1[ti][ks] = __builtin_bit_cast(bf16x8, u1);
        Whh1[ti][ks] = __builtin_bit_cast(bf16x8, u2);
      }
    }
  }
  // --- per-lane loop-invariant scalars (pre-scaled) ---
  const float wr0 = wih0[dim * 2] * S1,         wr1 = wih0[dim * 2 + 1] * S1;
  const float wz0 = wih0[(128 + dim) * 2] * S1, wz1 = wih0[(128 + dim) * 2 + 1] * S1;
  const float wn0 = wih0[(256 + dim) * 2] * S2, wn1 = wih0[(256 + dim) * 2 + 1] * S2;
  const float br0 = (bih0[dim] + bhh0[dim]) * S1;
  const float bz0 = (bih0[128 + dim] + bhh0[128 + dim]) * S1;
  const float bin0 = bih0[256 + dim] * S2, bhn0 = bhh0[256 + dim] * S2;
  const float br1 = (bih1[dim] + bhh1[dim]) * S1;
  const float bz1 = (bih1[128 + dim] + bhh1[128 + dim]) * S1;
  const float bin1 = bih1[256 + dim] * S2, bhn1 = bhh1[256 + dim] * S2;

  // --- init phase 0: stage small vectors, zero h ---
  for (int i = tid; i < 256; i += 512) waL[i] = w_a[i];
  if (tid < 128) { woL[tid] = w_o[stk * 128 + tid]; }
  for (int i = tid; i < 2 * 2176; i += 512) { ((unsigned short*)h0L)[i] = 0; ((unsigned short*)h1L)[i] = 0; }
  __syncthreads();
  // --- init phase 1: u vectors (u[d]=sum_m wc[m, off+d]*wo_h[m]) and Cc ---
  {
    const int task = tid >> 1, sub = tid & 1;       // task: 0..255
    const int which = task >> 7, d = task & 127;
    float acc = 0.f;
    const float* wcp = w_c + which * 128 + d + sub * 64 * 256;
    for (int m = 0; m < 64; ++m) acc += wcp[m * 256] * woL[sub * 64 + m];
    acc += __shfl_xor(acc, 1);
    if (sub == 0) uL[task] = acc;
  }
  if (tid < 128) red[tid] = b_c[tid] * woL[tid];
  __syncthreads();
  if (tid < 64) {
    float v = red[tid] + red[tid + 64];
    v += __shfl_xor(v, 1); v += __shfl_xor(v, 2); v += __shfl_xor(v, 4);
    v += __shfl_xor(v, 8); v += __shfl_xor(v, 16); v += __shfl_xor(v, 32);
    if (tid == 0) CcL = v;
  }
  __syncthreads();
  const float Cc = CcL;
  // --- dot-MFMA B-fragment: cols 0..3 = wa_p | u1 | u2 | wo_h ---
  bf16x8 Vb[4];
  {
#pragma unroll
    for (int ks = 0; ks < 4; ++ks) {
      ushort8 u;
#pragma unroll
      for (int j = 0; j < 8; ++j) {
        const int k = ks * 32 + lquad * 8 + j;
        float v = 0.f;
        if (lcol == 0) v = waL[128 + k];
        else if (lcol == 1) v = uL[k];
        else if (lcol == 2) v = uL[128 + k];
        else if (lcol == 3) v = woL[k];
        u[j] = f2bf(v);
      }
      Vb[ks] = __builtin_bit_cast(bf16x8, u);
    }
  }

  float h0m[4] = {0.f, 0.f, 0.f, 0.f};   // fp32 master h, rows lquad*4+j, col dim
  float h1m[4] = {0.f, 0.f, 0.f, 0.f};

  const int srow = tid >> 5;             // xs staging: 32 threads/row
  const int scol = (tid & 31) * 4;
  const int hAbase = lcol * 136;         // A-fragment read addressing
  int aofs[4];
#pragma unroll
  for (int ks = 0; ks < 4; ++ks)
    aofs[ks] = ((ks * 32 + lquad * 8 + ((lcol & 8) << 1)) & 127);
  int wofs[4];
#pragma unroll
  for (int j = 0; j < 4; ++j) wofs[j] = hoff(lquad * 4 + j, dim);

#pragma unroll 2
  for (int i = 0; i < L_ + 3; ++i) {     // 512 steps + 3 drain iterations
    const int rb = i & 1, wb = rb ^ 1;
    if (i < L_ && (i & 63) == 0) {       // stage next 64 steps of input
      const float4 v = *(const float4*)&recv[(size_t)(b0 + srow) * (L_ * NIN_) + i * NIN_ + scol];
      *(float4*)&xs[srow][scol] = v;
      __syncthreads();
    }

    if (i < L_) {
      // ---- layer0 t=i + layer1 t=i-1: 9 MFMAs x 4 ksteps ----
      floatx4 aR = {0.f,0.f,0.f,0.f}, aZ = {0.f,0.f,0.f,0.f}, aN = {0.f,0.f,0.f,0.f};
      floatx4 bR = {0.f,0.f,0.f,0.f}, bZ = {0.f,0.f,0.f,0.f};
      floatx4 bGi = {0.f,0.f,0.f,0.f}, bGh = {0.f,0.f,0.f,0.f};
#pragma unroll
      for (int ks = 0; ks < 4; ++ks) {
        bf16x8 a0 = *(const bf16x8*)&h0L[rb][hAbase + aofs[ks]];  // h0(i-1)
        bf16x8 a1 = *(const bf16x8*)&h1L[rb][hAbase + aofs[ks]];  // h1(i-2)
        aR  = mfma16(a0, Whh0[0][ks], aR);
        aZ  = mfma16(a0, Whh0[1][ks], aZ);
        aN  = mfma16(a0, Whh0[2][ks], aN);
        bR  = mfma16(a0, Wih1[0][ks], bR);
        bZ  = mfma16(a0, Wih1[1][ks], bZ);
        bGi = mfma16(a0, Wih1[2][ks], bGi);
        bR  = mfma16(a1, Whh1[0][ks], bR);
        bZ  = mfma16(a1, Whh1[1][ks], bZ);
        bGh = mfma16(a1, Whh1[2][ks], bGh);
      }
      const int tl = i & 63;
      // ---- layer0 update (t=i), in registers ----
#pragma unroll
      for (int j = 0; j < 4; ++j) {
        const float2 xv = *(const float2*)&xs[lquad * 4 + j][2 * tl];
        const float rg = sigp(fmaf(xv.x, wr0, fmaf(xv.y, wr1, aR[j] + br0)));
        const float zg = sigp(fmaf(xv.x, wz0, fmaf(xv.y, wz1, aZ[j] + bz0)));
        const float ng = fmaf(2.f, sigp(fmaf(rg, aN[j] + bhn0,
                              fmaf(xv.x, wn0, fmaf(xv.y, wn1, bin0)))), -1.f);
        h0m[j] = fmaf(zg, h0m[j] - ng, ng);
        h0L[wb][wofs[j]] = f2bf(h0m[j]);
      }
      // ---- layer1 update (t=i-1) ----
      if (i > 0) {
#pragma unroll
        for (int j = 0; j < 4; ++j) {
          const float rg = sigp(bR[j] + br1);
          const float zg = sigp(bZ[j] + bz1);
          const float ng = fmaf(2.f, sigp(fmaf(rg, bGh[j] + bhn1, bGi[j] + bin1)), -1.f);
          h1m[j] = fmaf(zg, h1m[j] - ng, ng);
          h1L[wb][wofs[j]] = f2bf(h1m[j]);
        }
      }
    } else if (i == L_) {
      // ---- drain: layer1 t=511 only ----
      floatx4 bR = {0.f,0.f,0.f,0.f}, bZ = {0.f,0.f,0.f,0.f};
      floatx4 bGi = {0.f,0.f,0.f,0.f}, bGh = {0.f,0.f,0.f,0.f};
#pragma unroll
      for (int ks = 0; ks < 4; ++ks) {
        bf16x8 a0 = *(const bf16x8*)&h0L[rb][hAbase + aofs[ks]];  // h0(511)
        bf16x8 a1 = *(const bf16x8*)&h1L[rb][hAbase + aofs[ks]];  // h1(510)
        bR  = mfma16(a0, Wih1[0][ks], bR);
        bZ  = mfma16(a0, Wih1[1][ks], bZ);
        bGi = mfma16(a0, Wih1[2][ks], bGi);
        bR  = mfma16(a1, Whh1[0][ks], bR);
        bZ  = mfma16(a1, Whh1[1][ks], bZ);
        bGh = mfma16(a1, Whh1[2][ks], bGh);
      }
#pragma unroll
      for (int j = 0; j < 4; ++j) {
        const float rg = sigp(bR[j] + br1);
        const float zg = sigp(bZ[j] + bz1);
        const float ng = fmaf(2.f, sigp(fmaf(rg, bGh[j] + bhn1, bGi[j] + bin1)), -1.f);
        h1m[j] = fmaf(zg, h1m[j] - ng, ng);
        h1L[wb][wofs[j]] = f2bf(h1m[j]);
      }
    }

    // ---- wave0: attention scalars for tau=i-2 (one MFMA on h1(tau)) ----
    if (wave == 0 && i >= 2 && i <= L_ + 1) {
      floatx4 d = {0.f,0.f,0.f,0.f};
#pragma unroll
      for (int ks = 0; ks < 4; ++ks)
        d = mfma16(*(const bf16x8*)&h1L[rb][hAbase + aofs[ks]], Vb[ks], d);
      if (lcol < 4)
        *(floatx4*)&SR[lcol][(i - 2) & 7][lquad * 4] = d;   // [col][slot][4 rows]
    }
    // ---- wave1 lanes<16: softmax + dec for p=i-3 ----
    if (wave == 1 && lane < 16 && i >= 3) {
      const int p = i - 3, slot = p & 7, row = lane;
      float dec;
      if (p >= ATTN_) {
        float e[ATTN_], mx = -1e30f;
#pragma unroll
        for (int j = 0; j < ATTN_; ++j) { e[j] = SR[0][(p - 5 + j) & 7][row]; mx = fmaxf(mx, e[j]); }
        float s = 0.f, q = 0.f;
#pragma unroll
        for (int j = 0; j < ATTN_; ++j) {
          const float w = __expf(e[j] - mx);
          s += w;
          q = fmaf(w, SR[1][(p - 5 + j) & 7][row], q);
        }
        dec = q * __builtin_amdgcn_rcpf(s) + SR[2][slot][row] + Cc;
      } else {
        dec = SR[3][slot][row];                 // passthrough: r[p].wo_half
      }
      decring[row][slot] = dec;
      if (slot == 7) {                          // burst-store 8 positions
        const float4 v0 = *(const float4*)&decring[row][0];
        const float4 v1 = *(const float4*)&decring[row][4];
        float* dst = dout + (size_t)(b0 + row) * L_ + (p - 7);
        *(float4*)dst = v0;
        *(float4*)(dst + 4) = v1;
      }
    }
    __syncthreads();
  }
}

// ---------------------------------------------------------------------------
// Final combine: out[b,t] = sigmoid(dec1[b,t] + dec2[b,min(t+10,511)] + b_o)
// ---------------------------------------------------------------------------
__global__ __launch_bounds__(512)
void combine_kernel(const float* __restrict__ dec1, const float* __restrict__ dec2,
                    const float* __restrict__ b_o, float* __restrict__ out)
{
  const int b = blockIdx.x, t = threadIdx.x;
  const int dt = (t + DLY_ < L_) ? t + DLY_ : L_ - 1;
  out[(size_t)b * L_ + t] = sigm(dec1[(size_t)b * L_ + t] + dec2[(size_t)b * L_ + dt] + b_o[0]);
}

extern "C" void kernel_launch(void* const* d_in, const int* in_sizes, int n_in,
                              void* d_out, int out_size, void* d_ws, size_t ws_size,
                              hipStream_t stream) {
  const float* recv   = (const float*)d_in[0];
  const float* wih1l0 = (const float*)d_in[1];
  const float* whh1l0 = (const float*)d_in[2];
  const float* bih1l0 = (const float*)d_in[3];
  const float* bhh1l0 = (const float*)d_in[4];
  const float* wih1l1 = (const float*)d_in[5];
  const float* whh1l1 = (const float*)d_in[6];
  const float* bih1l1 = (const float*)d_in[7];
  const float* bhh1l1 = (const float*)d_in[8];
  const float* wih2l0 = (const float*)d_in[9];
  const float* whh2l0 = (const float*)d_in[10];
  const float* bih2l0 = (const float*)d_in[11];
  const float* bhh2l0 = (const float*)d_in[12];
  const float* wih2l1 = (const float*)d_in[13];
  const float* whh2l1 = (const float*)d_in[14];
  const float* bih2l1 = (const float*)d_in[15];
  const float* bhh2l1 = (const float*)d_in[16];
  const float* w_a    = (const float*)d_in[17];
  const float* b_a    = (const float*)d_in[18]; (void)b_a; // uniform: cancels in softmax
  const float* w_c    = (const float*)d_in[19];
  const float* b_c    = (const float*)d_in[20];
  const float* w_o    = (const float*)d_in[21];
  const float* b_o    = (const float*)d_in[22];
  // d_in[23]=attn_num(5), d_in[24]=d_delay(10): compile-time constants here

  float* dec1 = (float*)d_ws;                 // (B,L) fp32 decoder partial, stack1
  float* dec2 = dec1 + (size_t)B_ * L_;       // (B,L) fp32 decoder partial, stack2

  gru_stack_kernel<<<128, 512, 0, stream>>>(
      recv,
      wih1l0, whh1l0, bih1l0, bhh1l0, wih1l1, whh1l1, bih1l1, bhh1l1,
      wih2l0, whh2l0, bih2l0, bhh2l0, wih2l1, whh2l1, bih2l1, bhh2l1,
      w_a, w_c, b_c, w_o, dec1, dec2);

  combine_kernel<<<B_, 512, 0, stream>>>(dec1, dec2, b_o, (float*)d_out);
}